// Round 17
// baseline (356.895 us; speedup 1.0000x reference)
//
#include <hip/hip_runtime.h>
#include <hip/hip_bf16.h>

#define NN   100000   // nodes
#define EE   500000   // edges
#define MPAD 100096   // 782 * 128
#define NBKT 782      // src buckets (src>>7)
#define NCHUNK 62500  // EE / 8 edges-per-wave-iter

using bf16x8 = __attribute__((ext_vector_type(8))) short;
using f32x4  = __attribute__((ext_vector_type(4))) float;
using u16x8  = __attribute__((ext_vector_type(8))) unsigned short;

__device__ __forceinline__ unsigned short f2bf(float f) {
  unsigned int x = __builtin_bit_cast(unsigned int, f);
  x += 0x7fffu + ((x >> 16) & 1u);           // round-to-nearest-even
  return (unsigned short)(x >> 16);
}
__device__ __forceinline__ float bf2f(unsigned short u) {
  unsigned int x = ((unsigned int)u) << 16;
  return __builtin_bit_cast(float, x);
}
__device__ __forceinline__ unsigned short f2bh(float f) {
  return __builtin_bit_cast(unsigned short, __float2bfloat16(f));
}
__device__ __forceinline__ void glds16(const void* g, const void* l) {
  __builtin_amdgcn_global_load_lds((const __attribute__((address_space(1))) void*)g,
                                   (__attribute__((address_space(3))) void*)l, 16, 0, 0);
}

// ---------------- Pass 1: WT[j][k] = bf16(W1[k + 256*(j>=256)][j&255]) ----------------
__global__ void wprep_kernel(const float* __restrict__ W1, unsigned short* __restrict__ WT) {
  int id = blockIdx.x * blockDim.x + threadIdx.x;
  if (id >= 512 * 32) return;
  int j  = id >> 5;
  int cg = id & 31;
  int jc = j & 255;
  int kb = (cg << 3) + ((j >= 256) ? 256 : 0);
  u16x8 v;
#pragma unroll
  for (int t = 0; t < 8; ++t)
    v[t] = f2bf(W1[(size_t)(kb + t) * 256 + jc]);
  *reinterpret_cast<u16x8*>(WT + (size_t)j * 256 + (cg << 3)) = v;
}

// ---------------- Sort pass A: zero bins ----------------
__global__ __launch_bounds__(256) void zero_bins(int* __restrict__ bins) {
  for (int i = threadIdx.x; i < NBKT; i += 256) bins[i] = 0;
}
// ---------------- Sort pass B: histogram of src>>7 ----------------
__global__ __launch_bounds__(256) void hist_kernel(const int* __restrict__ idx,
                                                   int* __restrict__ bins) {
  for (int e = blockIdx.x * blockDim.x + threadIdx.x; e < EE;
       e += gridDim.x * blockDim.x)
    atomicAdd(&bins[idx[e] >> 7], 1);
}
// ---------------- Sort pass C: exclusive scan (one block) -> cursor ----------------
__global__ __launch_bounds__(1024) void scan_kernel(const int* __restrict__ bins,
                                                    int* __restrict__ cursor) {
  __shared__ int sm[1024];
  const int t = threadIdx.x;
  const int v0 = (t < NBKT) ? bins[t] : 0;
  sm[t] = v0;
  __syncthreads();
#pragma unroll
  for (int off = 1; off < 1024; off <<= 1) {
    int v = (t >= off) ? sm[t - off] : 0;
    __syncthreads();
    sm[t] += v;
    __syncthreads();
  }
  if (t < NBKT) cursor[t] = sm[t] - v0;          // exclusive prefix
}
// ---------------- Sort pass D: scatter edges into bucket order ----------------
__global__ __launch_bounds__(256) void scatter_kernel(const int* __restrict__ idx,
                                                      int* __restrict__ cursor,
                                                      int* __restrict__ ss,
                                                      int* __restrict__ dd,
                                                      int* __restrict__ pe) {
  for (int e = blockIdx.x * blockDim.x + threadIdx.x; e < EE;
       e += gridDim.x * blockDim.x) {
    const int s = idx[e];
    const int p = atomicAdd(&cursor[s >> 7], 1);
    ss[p] = s;
    dd[p] = idx[EE + e];
    pe[p] = e;
  }
}

// ---------------- Pass 2 (R15 / timed-best): pure-glds GEMM, A staged as RAW FP32 ------
__global__ __launch_bounds__(256, 3) void gemm_pq(const float* __restrict__ emb,
                                                  const unsigned short* __restrict__ WT,
                                                  const float* __restrict__ b1,
                                                  unsigned short* __restrict__ R) {
  __shared__ float          ldsA[2][128 * 32];
  __shared__ unsigned short ldsB[2][128 * 32];

  const int t    = threadIdx.x;
  const int lane = t & 63;
  const int wave = t >> 6;
  const int wrow = wave >> 1, wcol = wave & 1;
  const int bid = (int)blockIdx.x;
  const int lid = (bid & 7) * 391 + (bid >> 3);
  const int m0 = (lid >> 2) * 128;
  const int n0 = (lid & 3) * 128;

  size_t aOffG[4]; int aLds[4];
#pragma unroll
  for (int i = 0; i < 4; ++i) {
    const int r  = wave * 32 + i * 8 + (lane >> 3);
    const int cp = lane & 7;
    const int g  = cp ^ (r & 7);
    int rg = m0 + r; if (rg >= NN) rg = NN - 1;
    aOffG[i] = (size_t)rg * 256 + (g << 2);
    aLds[i]  = (wave * 32 + i * 8) * 32;
  }
  size_t bOffG[2]; int bLds[2];
#pragma unroll
  for (int i = 0; i < 2; ++i) {
    const int r  = wave * 32 + i * 16 + (lane >> 2);
    const int qp = lane & 3;
    const int g  = qp ^ ((r >> 1) & 3);
    bOffG[i] = (size_t)(n0 + r) * 256 + (g << 3);
    bLds[i]  = (wave * 32 + i * 16) * 32;
  }

  const int fr = lane & 15, fq = lane >> 4;
  int aoff0[4], aoff1[4], boff[4];
#pragma unroll
  for (int m = 0; m < 4; ++m) {
    const int r  = wrow * 64 + 16 * m + fr;
    const int s0 = ((fq << 1) | 0) ^ (r & 7);
    const int s1 = ((fq << 1) | 1) ^ (r & 7);
    aoff0[m] = r * 32 + (s0 << 2);
    aoff1[m] = r * 32 + (s1 << 2);
  }
#pragma unroll
  for (int n = 0; n < 4; ++n) {
    const int r = wcol * 64 + 16 * n + fr;
    boff[n] = r * 32 + ((fq ^ ((r >> 1) & 3)) << 3);
  }

#define STAGE(buf, ks)                                                         \
  do {                                                                         \
    glds16(emb + aOffG[0] + ((ks) << 5), &ldsA[(buf)][aLds[0]]);               \
    glds16(emb + aOffG[1] + ((ks) << 5), &ldsA[(buf)][aLds[1]]);               \
    glds16(emb + aOffG[2] + ((ks) << 5), &ldsA[(buf)][aLds[2]]);               \
    glds16(emb + aOffG[3] + ((ks) << 5), &ldsA[(buf)][aLds[3]]);               \
    glds16(WT + bOffG[0] + ((ks) << 5), &ldsB[(buf)][bLds[0]]);                \
    glds16(WT + bOffG[1] + ((ks) << 5), &ldsB[(buf)][bLds[1]]);                \
  } while (0)

  f32x4 acc[4][4] = {};
  STAGE(0, 0);
  __syncthreads();

#pragma unroll
  for (int ks = 0; ks < 8; ++ks) {
    const int p = ks & 1;
    if (ks < 7) STAGE(p ^ 1, ks + 1);
    bf16x8 av[4], bv[4];
#pragma unroll
    for (int m = 0; m < 4; ++m) {
      const float4 x0 = *(const float4*)&ldsA[p][aoff0[m]];
      const float4 x1 = *(const float4*)&ldsA[p][aoff1[m]];
      bf16x8 a;
      a[0] = (short)f2bh(x0.x); a[1] = (short)f2bh(x0.y);
      a[2] = (short)f2bh(x0.z); a[3] = (short)f2bh(x0.w);
      a[4] = (short)f2bh(x1.x); a[5] = (short)f2bh(x1.y);
      a[6] = (short)f2bh(x1.z); a[7] = (short)f2bh(x1.w);
      av[m] = a;
    }
#pragma unroll
    for (int n = 0; n < 4; ++n) bv[n] = *(const bf16x8*)&ldsB[p][boff[n]];
#pragma unroll
    for (int m = 0; m < 4; ++m)
#pragma unroll
      for (int n = 0; n < 4; ++n)
        acc[m][n] = __builtin_amdgcn_mfma_f32_16x16x32_bf16(av[m], bv[n], acc[m][n], 0, 0, 0);
    if (ks < 7) __syncthreads();
  }

  float bn[4];
#pragma unroll
  for (int n = 0; n < 4; ++n) {
    const int c = n0 + wcol * 64 + 16 * n + fr;
    bn[n] = (c < 256) ? b1[c] : 0.f;
  }
#pragma unroll
  for (int m = 0; m < 4; ++m) {
    const int r0 = m0 + wrow * 64 + 16 * m + (fq << 2);
#pragma unroll
    for (int n = 0; n < 4; ++n) {
      const int c = n0 + wcol * 64 + 16 * n + fr;
#pragma unroll
      for (int i = 0; i < 4; ++i)
        R[(size_t)(r0 + i) * 512 + c] = f2bh(acc[m][n][i] + bn[n]);
    }
  }
#undef STAGE
}

// ---------------- Pass 3 (R17): sorted edges, XCD-chunked, 8 edges/wave-iter ----------
// Each XCD owns a contiguous range of src-sorted edges -> bucket src rows (98KB) go
// L2-resident, cutting L3->L2 line fills ~40%.
__global__ __launch_bounds__(256) void edge_sorted(const int* __restrict__ ss,
                                                   const int* __restrict__ dd,
                                                   const int* __restrict__ pe,
                                                   const unsigned short* __restrict__ R,
                                                   const float* __restrict__ W2,
                                                   const float* __restrict__ b2,
                                                   float* __restrict__ out) {
  const int lane = threadIdx.x & 63;
  const int half = lane >> 5;
  const int l    = lane & 31;
  const int b    = (int)blockIdx.x;            // 2048 blocks
  const int xcd  = b & 7;
  const int wl   = (b >> 3) * 4 + (threadIdx.x >> 6);   // local wave id on this XCD: 0..1023
  const int base = xcd * 7813;                 // ceil(62500/8) chunking
  const int cnt  = min(7813, NCHUNK - base);
  const float4 w0 = *(const float4*)(W2 + (l << 3));
  const float4 w1 = *(const float4*)(W2 + (l << 3) + 4);
  const float bias = b2[0];

  for (int c = wl; c < cnt; c += 1024) {
    const int e0 = (base + c) << 3;
    int s[4], d[4], o[4];
#pragma unroll
    for (int u = 0; u < 4; ++u) {
      const int ei = e0 + (u << 1) + half;
      s[u] = ss[ei];
      d[u] = dd[ei];
      o[u] = pe[ei];
    }
    u16x8 ga[4], gb[4];
#pragma unroll
    for (int u = 0; u < 4; ++u) {
      ga[u] = *(const u16x8*)(R + (size_t)s[u] * 512 + (l << 3));
      gb[u] = *(const u16x8*)(R + (size_t)d[u] * 512 + 256 + (l << 3));
    }
#pragma unroll
    for (int u = 0; u < 4; ++u) {
      float acc;
      acc  = fmaxf(bf2f((unsigned short)ga[u][0]) + bf2f((unsigned short)gb[u][0]), 0.f) * w0.x;
      acc += fmaxf(bf2f((unsigned short)ga[u][1]) + bf2f((unsigned short)gb[u][1]), 0.f) * w0.y;
      acc += fmaxf(bf2f((unsigned short)ga[u][2]) + bf2f((unsigned short)gb[u][2]), 0.f) * w0.z;
      acc += fmaxf(bf2f((unsigned short)ga[u][3]) + bf2f((unsigned short)gb[u][3]), 0.f) * w0.w;
      acc += fmaxf(bf2f((unsigned short)ga[u][4]) + bf2f((unsigned short)gb[u][4]), 0.f) * w1.x;
      acc += fmaxf(bf2f((unsigned short)ga[u][5]) + bf2f((unsigned short)gb[u][5]), 0.f) * w1.y;
      acc += fmaxf(bf2f((unsigned short)ga[u][6]) + bf2f((unsigned short)gb[u][6]), 0.f) * w1.z;
      acc += fmaxf(bf2f((unsigned short)ga[u][7]) + bf2f((unsigned short)gb[u][7]), 0.f) * w1.w;
#pragma unroll
      for (int off = 16; off > 0; off >>= 1) acc += __shfl_xor(acc, off, 64);
      if (l == 0) out[o[u]] = acc + bias;
    }
  }
}

// ---------------- Pass 3 (unsorted mid-fallback, R15-proven) ----------------
__global__ __launch_bounds__(256) void edge_kernel(const int* __restrict__ idx,
                                                   const unsigned short* __restrict__ R,
                                                   const float* __restrict__ W2,
                                                   const float* __restrict__ b2,
                                                   float* __restrict__ out) {
  const int lane  = threadIdx.x & 63;
  const int half  = lane >> 5;
  const int l     = lane & 31;
  const int gwave = (int)((blockIdx.x * blockDim.x + threadIdx.x) >> 6);
  const int nwave = (int)((gridDim.x * blockDim.x) >> 6);
  const float4 w0 = *(const float4*)(W2 + (l << 3));
  const float4 w1 = *(const float4*)(W2 + (l << 3) + 4);
  const float bias = b2[0];
  for (int c = gwave; c < (EE / 8); c += nwave) {
    const int e0 = c << 3;
    int s[4], d[4];
#pragma unroll
    for (int u = 0; u < 4; ++u) {
      s[u] = idx[e0 + (u << 1) + half];
      d[u] = idx[EE + e0 + (u << 1) + half];
    }
    u16x8 ga[4], gb[4];
#pragma unroll
    for (int u = 0; u < 4; ++u) {
      ga[u] = *(const u16x8*)(R + (size_t)s[u] * 512 + (l << 3));
      gb[u] = *(const u16x8*)(R + (size_t)d[u] * 512 + 256 + (l << 3));
    }
#pragma unroll
    for (int u = 0; u < 4; ++u) {
      float acc;
      acc  = fmaxf(bf2f((unsigned short)ga[u][0]) + bf2f((unsigned short)gb[u][0]), 0.f) * w0.x;
      acc += fmaxf(bf2f((unsigned short)ga[u][1]) + bf2f((unsigned short)gb[u][1]), 0.f) * w0.y;
      acc += fmaxf(bf2f((unsigned short)ga[u][2]) + bf2f((unsigned short)gb[u][2]), 0.f) * w0.z;
      acc += fmaxf(bf2f((unsigned short)ga[u][3]) + bf2f((unsigned short)gb[u][3]), 0.f) * w0.w;
      acc += fmaxf(bf2f((unsigned short)ga[u][4]) + bf2f((unsigned short)gb[u][4]), 0.f) * w1.x;
      acc += fmaxf(bf2f((unsigned short)ga[u][5]) + bf2f((unsigned short)gb[u][5]), 0.f) * w1.y;
      acc += fmaxf(bf2f((unsigned short)ga[u][6]) + bf2f((unsigned short)gb[u][6]), 0.f) * w1.z;
      acc += fmaxf(bf2f((unsigned short)ga[u][7]) + bf2f((unsigned short)gb[u][7]), 0.f) * w1.w;
#pragma unroll
      for (int off = 16; off > 0; off >>= 1) acc += __shfl_xor(acc, off, 64);
      if (l == 0) out[e0 + (u << 1) + half] = acc + bias;
    }
  }
}

// ---------------- Fallback (tiny ws): direct, slow, correct ----------------
__global__ __launch_bounds__(256) void fallback_kernel(const float* __restrict__ emb,
                                                       const int* __restrict__ idx,
                                                       const float* __restrict__ W1,
                                                       const float* __restrict__ b1,
                                                       const float* __restrict__ W2,
                                                       const float* __restrict__ b2,
                                                       float* __restrict__ out) {
  __shared__ float feats[512];
  __shared__ float red[256];
  const int t = threadIdx.x;
  for (int e = blockIdx.x; e < EE; e += gridDim.x) {
    __syncthreads();
    const int s = idx[e], d = idx[EE + e];
    feats[t]       = emb[(size_t)s * 256 + t];
    feats[256 + t] = emb[(size_t)d * 256 + t];
    __syncthreads();
    float h = b1[t];
    for (int k = 0; k < 512; ++k) h += feats[k] * W1[k * 256 + t];
    red[t] = fmaxf(h, 0.f) * W2[t];
    __syncthreads();
    for (int off = 128; off > 0; off >>= 1) {
      if (t < off) red[t] += red[t + off];
      __syncthreads();
    }
    if (t == 0) out[e] = red[0] + b2[0];
  }
}

extern "C" void kernel_launch(void* const* d_in, const int* in_sizes, int n_in,
                              void* d_out, int out_size, void* d_ws, size_t ws_size,
                              hipStream_t stream) {
  const float* emb = (const float*)d_in[0];
  const int*   idx = (const int*)d_in[1];
  const float* W1  = (const float*)d_in[2];
  const float* b1  = (const float*)d_in[3];
  const float* W2  = (const float*)d_in[4];
  const float* b2  = (const float*)d_in[5];
  float* out = (float*)d_out;

  const size_t wt_elems = (size_t)512 * 256;
  const size_t r_elems  = (size_t)MPAD * 512;
  const size_t base_bytes = (wt_elems + r_elems) * sizeof(unsigned short);
  // sort arrays: bins + cursor + ss + dd + pe (ints), 16B-aligned start
  const size_t sort_ints  = (size_t)NBKT * 2 + (size_t)EE * 3 + 8;
  const size_t need_sort  = base_bytes + 16 + sort_ints * sizeof(int);

  unsigned short* WT = (unsigned short*)d_ws;
  unsigned short* R  = WT + wt_elems;
  char* tail = (char*)(R + r_elems);
  int* bins   = (int*)((((uintptr_t)tail) + 15) & ~(uintptr_t)15);
  int* cursor = bins + NBKT;
  int* ss     = cursor + NBKT;
  int* dd     = ss + EE;
  int* pe     = dd + EE;

  if (ws_size >= need_sort) {
    wprep_kernel<<<64, 256, 0, stream>>>(W1, WT);
    zero_bins<<<1, 256, 0, stream>>>(bins);
    hist_kernel<<<512, 256, 0, stream>>>(idx, bins);
    scan_kernel<<<1, 1024, 0, stream>>>(bins, cursor);
    scatter_kernel<<<512, 256, 0, stream>>>(idx, cursor, ss, dd, pe);
    gemm_pq<<<(MPAD / 128) * 4, 256, 0, stream>>>(emb, WT, b1, R);
    edge_sorted<<<2048, 256, 0, stream>>>(ss, dd, pe, R, W2, b2, out);
  } else if (ws_size >= base_bytes) {
    wprep_kernel<<<64, 256, 0, stream>>>(W1, WT);
    gemm_pq<<<(MPAD / 128) * 4, 256, 0, stream>>>(emb, WT, b1, R);
    edge_kernel<<<2048, 256, 0, stream>>>(idx, R, W2, b2, out);
  } else {
    fallback_kernel<<<4096, 256, 0, stream>>>(emb, idx, W1, b1, W2, b2, out);
  }
}

// Round 18
// 133.029 us; speedup vs baseline: 2.6828x; 2.6828x over previous
//
#include <hip/hip_runtime.h>
#include <hip/hip_bf16.h>

#define NN   100000   // nodes
#define EE   500000   // edges
#define MPAD 100096   // 782 * 128

using bf16x8 = __attribute__((ext_vector_type(8))) short;
using f32x4  = __attribute__((ext_vector_type(4))) float;
using u16x8  = __attribute__((ext_vector_type(8))) unsigned short;

__device__ __forceinline__ unsigned short f2bf(float f) {
  unsigned int x = __builtin_bit_cast(unsigned int, f);
  x += 0x7fffu + ((x >> 16) & 1u);           // round-to-nearest-even
  return (unsigned short)(x >> 16);
}
__device__ __forceinline__ float bf2f(unsigned short u) {
  unsigned int x = ((unsigned int)u) << 16;
  return __builtin_bit_cast(float, x);
}
// HW RNE cvt (compiler emits v_cvt_pk_bf16_f32 for pairs)
__device__ __forceinline__ unsigned short f2bh(float f) {
  return __builtin_bit_cast(unsigned short, __float2bfloat16(f));
}
__device__ __forceinline__ void glds16(const void* g, const void* l) {
  __builtin_amdgcn_global_load_lds((const __attribute__((address_space(1))) void*)g,
                                   (__attribute__((address_space(3))) void*)l, 16, 0, 0);
}

// ---------------- Pass 1: WT[j][k] = bf16(W1[k + 256*(j>=256)][j&255]) ----------------
__global__ void wprep_kernel(const float* __restrict__ W1, unsigned short* __restrict__ WT) {
  int id = blockIdx.x * blockDim.x + threadIdx.x;
  if (id >= 512 * 32) return;
  int j  = id >> 5;        // 0..511
  int cg = id & 31;        // 8-element k-chunk
  int jc = j & 255;
  int kb = (cg << 3) + ((j >= 256) ? 256 : 0);
  u16x8 v;
#pragma unroll
  for (int t = 0; t < 8; ++t)
    v[t] = f2bf(W1[(size_t)(kb + t) * 256 + jc]);
  *reinterpret_cast<u16x8*>(WT + (size_t)j * 256 + (cg << 3)) = v;
}

// ---------------- Pass 2 (R15 / session-best timed): pure-glds GEMM, A as RAW FP32 ------
// R[MPAD][512] = bf16(emb @ WT^T) (+ b1 on src half). 128x128 tile, BK=32, dbuf.
// A: fp32 via global_load_lds straight from emb (no cvt pre-pass, no reg round-trip);
//    8-slot involution chunk ^= (row&7) on pre-swizzled sources.
// B: bf16 via global_load_lds (proven path + swizzle). cvt_pk fp32->bf16 at
// fragment-read time. One barrier per K-step, XCD-bijective block swizzle, b1-fold.
// Timed best: 133.1us total in R15.
__global__ __launch_bounds__(256, 3) void gemm_pq(const float* __restrict__ emb,
                                                  const unsigned short* __restrict__ WT,
                                                  const float* __restrict__ b1,
                                                  unsigned short* __restrict__ R) {
  __shared__ float          ldsA[2][128 * 32];   // fp32, 8-slot swizzle (32 KB)
  __shared__ unsigned short ldsB[2][128 * 32];   // bf16, 4-slot swizzle (16 KB)

  const int t    = threadIdx.x;
  const int lane = t & 63;
  const int wave = t >> 6;
  const int wrow = wave >> 1, wcol = wave & 1;
  // XCD-bijective swizzle: 3128 = 8 * 391; n-tiles (lid&3) of one m-tile share an XCD L2.
  const int bid = (int)blockIdx.x;
  const int lid = (bid & 7) * 391 + (bid >> 3);
  const int m0 = (lid >> 2) * 128;
  const int n0 = (lid & 3) * 128;

  // ---- A staging (glds fp32): 4 instrs/wave/K-step, each 1 KB = 8 rows x 32 floats.
  //      lane -> row = base + (l>>3), chunk slot c' = l&7, source chunk g = c' ^ (row&7).
  size_t aOffG[4]; int aLds[4];
#pragma unroll
  for (int i = 0; i < 4; ++i) {
    const int r  = wave * 32 + i * 8 + (lane >> 3);
    const int cp = lane & 7;
    const int g  = cp ^ (r & 7);                     // pre-swizzled source chunk
    int rg = m0 + r; if (rg >= NN) rg = NN - 1;      // clamp; pad rows unused
    aOffG[i] = (size_t)rg * 256 + (g << 2);          // float elems (chunk = 4 floats)
    aLds[i]  = (wave * 32 + i * 8) * 32;             // wave-uniform base (float elems)
  }
  // ---- B staging (glds bf16): 2 instrs/wave/K-step.
  size_t bOffG[2]; int bLds[2];
#pragma unroll
  for (int i = 0; i < 2; ++i) {
    const int r  = wave * 32 + i * 16 + (lane >> 2);
    const int qp = lane & 3;
    const int g  = qp ^ ((r >> 1) & 3);
    bOffG[i] = (size_t)(n0 + r) * 256 + (g << 3);
    bLds[i]  = (wave * 32 + i * 16) * 32;
  }

  // ---- fragment read addressing
  const int fr = lane & 15, fq = lane >> 4;
  int aoff0[4], aoff1[4], boff[4];
#pragma unroll
  for (int m = 0; m < 4; ++m) {
    const int r  = wrow * 64 + 16 * m + fr;
    const int s0 = ((fq << 1) | 0) ^ (r & 7);        // swizzled slot of chunk 2fq
    const int s1 = ((fq << 1) | 1) ^ (r & 7);        // swizzled slot of chunk 2fq+1
    aoff0[m] = r * 32 + (s0 << 2);
    aoff1[m] = r * 32 + (s1 << 2);
  }
#pragma unroll
  for (int n = 0; n < 4; ++n) {
    const int r = wcol * 64 + 16 * n + fr;
    boff[n] = r * 32 + ((fq ^ ((r >> 1) & 3)) << 3);
  }

#define STAGE(buf, ks)                                                         \
  do {                                                                         \
    glds16(emb + aOffG[0] + ((ks) << 5), &ldsA[(buf)][aLds[0]]);               \
    glds16(emb + aOffG[1] + ((ks) << 5), &ldsA[(buf)][aLds[1]]);               \
    glds16(emb + aOffG[2] + ((ks) << 5), &ldsA[(buf)][aLds[2]]);               \
    glds16(emb + aOffG[3] + ((ks) << 5), &ldsA[(buf)][aLds[3]]);               \
    glds16(WT + bOffG[0] + ((ks) << 5), &ldsB[(buf)][bLds[0]]);                \
    glds16(WT + bOffG[1] + ((ks) << 5), &ldsB[(buf)][bLds[1]]);                \
  } while (0)

  f32x4 acc[4][4] = {};

  STAGE(0, 0);
  __syncthreads();

#pragma unroll
  for (int ks = 0; ks < 8; ++ks) {
    const int p = ks & 1;
    if (ks < 7) STAGE(p ^ 1, ks + 1);            // fire-and-forget DMA of next tile
    bf16x8 av[4], bv[4];
#pragma unroll
    for (int m = 0; m < 4; ++m) {
      const float4 x0 = *(const float4*)&ldsA[p][aoff0[m]];
      const float4 x1 = *(const float4*)&ldsA[p][aoff1[m]];
      bf16x8 a;
      a[0] = (short)f2bh(x0.x); a[1] = (short)f2bh(x0.y);
      a[2] = (short)f2bh(x0.z); a[3] = (short)f2bh(x0.w);
      a[4] = (short)f2bh(x1.x); a[5] = (short)f2bh(x1.y);
      a[6] = (short)f2bh(x1.z); a[7] = (short)f2bh(x1.w);
      av[m] = a;
    }
#pragma unroll
    for (int n = 0; n < 4; ++n) bv[n] = *(const bf16x8*)&ldsB[p][boff[n]];
#pragma unroll
    for (int m = 0; m < 4; ++m)
#pragma unroll
      for (int n = 0; n < 4; ++n)
        acc[m][n] = __builtin_amdgcn_mfma_f32_16x16x32_bf16(av[m], bv[n], acc[m][n], 0, 0, 0);
    if (ks < 7) __syncthreads();
  }

  // epilogue: col = lane&15 (+16n), row = (lane>>4)*4 + i; m-outer/n-inner (clean 128B lines)
  float bn[4];
#pragma unroll
  for (int n = 0; n < 4; ++n) {
    const int c = n0 + wcol * 64 + 16 * n + fr;
    bn[n] = (c < 256) ? b1[c] : 0.f;
  }
#pragma unroll
  for (int m = 0; m < 4; ++m) {
    const int r0 = m0 + wrow * 64 + 16 * m + (fq << 2);
#pragma unroll
    for (int n = 0; n < 4; ++n) {
      const int c = n0 + wcol * 64 + 16 * n + fr;
#pragma unroll
      for (int i = 0; i < 4; ++i)
        R[(size_t)(r0 + i) * 512 + c] = f2bh(acc[m][n][i] + bn[n]);
    }
  }
#undef STAGE
}

// ---------------- Pass 3 (R15): 16 edges per wave-iteration (32 gathers in flight) ------
// score[e] = b2 + sum_j relu(R[src][j] + R[dst][256+j]) * W2[j]   (b1 pre-folded into R)
__global__ __launch_bounds__(256) void edge_kernel(const int* __restrict__ idx,
                                                   const unsigned short* __restrict__ R,
                                                   const float* __restrict__ W2,
                                                   const float* __restrict__ b2,
                                                   float* __restrict__ out) {
  const int lane  = threadIdx.x & 63;
  const int half  = lane >> 5;         // which of the 2 concurrent edges this lane serves
  const int l     = lane & 31;         // 32 lanes x 8 channels = 256 channels
  const int gwave = (int)((blockIdx.x * blockDim.x + threadIdx.x) >> 6);
  const int nwave = (int)((gridDim.x * blockDim.x) >> 6);
  const float4 w0 = *(const float4*)(W2 + (l << 3));
  const float4 w1 = *(const float4*)(W2 + (l << 3) + 4);
  const float bias = b2[0];

  for (int c = gwave; c < (EE / 16); c += nwave) {
    const int e0 = c << 4;
    int s[8], d[8];
#pragma unroll
    for (int u = 0; u < 8; ++u) {                // edge for this lane: e0 + 2u + half
      s[u] = idx[e0 + (u << 1) + half];
      d[u] = idx[EE + e0 + (u << 1) + half];
    }
    u16x8 ga[8], gb[8];
#pragma unroll
    for (int u = 0; u < 8; ++u) {                // issue all 32 gathers before reducing
      ga[u] = *(const u16x8*)(R + (size_t)s[u] * 512 + (l << 3));
      gb[u] = *(const u16x8*)(R + (size_t)d[u] * 512 + 256 + (l << 3));
    }
#pragma unroll
    for (int u = 0; u < 8; ++u) {
      float acc;
      acc  = fmaxf(bf2f((unsigned short)ga[u][0]) + bf2f((unsigned short)gb[u][0]), 0.f) * w0.x;
      acc += fmaxf(bf2f((unsigned short)ga[u][1]) + bf2f((unsigned short)gb[u][1]), 0.f) * w0.y;
      acc += fmaxf(bf2f((unsigned short)ga[u][2]) + bf2f((unsigned short)gb[u][2]), 0.f) * w0.z;
      acc += fmaxf(bf2f((unsigned short)ga[u][3]) + bf2f((unsigned short)gb[u][3]), 0.f) * w0.w;
      acc += fmaxf(bf2f((unsigned short)ga[u][4]) + bf2f((unsigned short)gb[u][4]), 0.f) * w1.x;
      acc += fmaxf(bf2f((unsigned short)ga[u][5]) + bf2f((unsigned short)gb[u][5]), 0.f) * w1.y;
      acc += fmaxf(bf2f((unsigned short)ga[u][6]) + bf2f((unsigned short)gb[u][6]), 0.f) * w1.z;
      acc += fmaxf(bf2f((unsigned short)ga[u][7]) + bf2f((unsigned short)gb[u][7]), 0.f) * w1.w;
#pragma unroll
      for (int off = 16; off > 0; off >>= 1) acc += __shfl_xor(acc, off, 64);
      if (l == 0) out[e0 + (u << 1) + half] = acc + bias;
    }
  }
}

// ---------------- Fallback (only if ws is too small): direct, slow, correct ----------------
__global__ __launch_bounds__(256) void fallback_kernel(const float* __restrict__ emb,
                                                       const int* __restrict__ idx,
                                                       const float* __restrict__ W1,
                                                       const float* __restrict__ b1,
                                                       const float* __restrict__ W2,
                                                       const float* __restrict__ b2,
                                                       float* __restrict__ out) {
  __shared__ float feats[512];
  __shared__ float red[256];
  const int t = threadIdx.x;
  for (int e = blockIdx.x; e < EE; e += gridDim.x) {
    __syncthreads();
    const int s = idx[e], d = idx[EE + e];
    feats[t]       = emb[(size_t)s * 256 + t];
    feats[256 + t] = emb[(size_t)d * 256 + t];
    __syncthreads();
    float h = b1[t];
    for (int k = 0; k < 512; ++k) h += feats[k] * W1[k * 256 + t];
    red[t] = fmaxf(h, 0.f) * W2[t];
    __syncthreads();
    for (int off = 128; off > 0; off >>= 1) {
      if (t < off) red[t] += red[t + off];
      __syncthreads();
    }
    if (t == 0) out[e] = red[0] + b2[0];
  }
}

extern "C" void kernel_launch(void* const* d_in, const int* in_sizes, int n_in,
                              void* d_out, int out_size, void* d_ws, size_t ws_size,
                              hipStream_t stream) {
  const float* emb = (const float*)d_in[0];
  const int*   idx = (const int*)d_in[1];
  const float* W1  = (const float*)d_in[2];
  const float* b1  = (const float*)d_in[3];
  const float* W2  = (const float*)d_in[4];
  const float* b2  = (const float*)d_in[5];
  float* out = (float*)d_out;

  const size_t wt_elems = (size_t)512 * 256;
  const size_t r_elems  = (size_t)MPAD * 512;
  const size_t need = (wt_elems + r_elems) * sizeof(unsigned short);

  if (ws_size < need) {
    fallback_kernel<<<4096, 256, 0, stream>>>(emb, idx, W1, b1, W2, b2, out);
    return;
  }

  unsigned short* WT = (unsigned short*)d_ws;
  unsigned short* R  = WT + wt_elems;

  wprep_kernel<<<64, 256, 0, stream>>>(W1, WT);
  gemm_pq<<<(MPAD / 128) * 4, 256, 0, stream>>>(emb, WT, b1, R);
  edge_kernel<<<2048, 256, 0, stream>>>(idx, R, W2, b2, out);
}